// Round 1
// baseline (119.838 us; speedup 1.0000x reference)
//
#include <hip/hip_runtime.h>
#include <math.h>

#define NG 2048
#define IMG_W 128
#define IMG_H 128
#define NPIX (IMG_W * IMG_H)
#define ALPHA_MIN (1.0f / 255.0f)

// ws layout:
//   [0, 8K)        : int ranks[2048]
//   [8K, 8K+80K)   : z-sorted SoA float arrays (each NG):
//                    px, py, rc2, conA, conB, conC, op, colr, colg, colb

// ---------------------------------------------------------------------------
// Stable rank of each gaussian under z-ascending order (ties broken by index),
// matching jnp.argsort (stable). 64 blocks: 8 i-chunks x 8 j-chunks, atomicAdd.
__global__ void __launch_bounds__(256) rank_kernel(const float* __restrict__ means,
                                                   int* __restrict__ ranks) {
    __shared__ float zs[256];
    const int t  = threadIdx.x;
    const int bi = blockIdx.x & 7;   // i-chunk
    const int bk = blockIdx.x >> 3;  // j-chunk
    const int j0 = bk * 256;
    zs[t] = means[(j0 + t) * 3 + 2];
    const int i = bi * 256 + t;
    const float zi = means[i * 3 + 2];
    __syncthreads();
    int cnt = 0;
#pragma unroll 4
    for (int j = 0; j < 256; ++j) {
        const float zj = zs[j];
        cnt += (zj < zi || (zj == zi && (j0 + j) < i)) ? 1 : 0;
    }
    atomicAdd(&ranks[i], cnt);
}

// ---------------------------------------------------------------------------
// Per-gaussian projection/conic in double precision; scatter into sorted SoA.
__global__ void __launch_bounds__(256) prep_kernel(const float* __restrict__ means,
                                                   const float* __restrict__ colors,
                                                   const float* __restrict__ opac,
                                                   const float* __restrict__ cov3,
                                                   const int* __restrict__ ranks,
                                                   float* __restrict__ radii_out,
                                                   float* __restrict__ soa) {
    const int i = blockIdx.x * 256 + threadIdx.x;
    if (i >= NG) return;
    const double x = means[i * 3 + 0];
    const double y = means[i * 3 + 1];
    const double z = means[i * 3 + 2];
    const double inv_z = 1.0 / z;
    const double fx = 128.0, fy = 128.0, lim = 0.65;  // W/(2*tanfov), 1.3*tanfov
    const double px = fx * x * inv_z + 64.0;
    const double py = fy * y * inv_z + 64.0;
    double tx = x * inv_z; tx = fmin(fmax(tx, -lim), lim); tx *= z;
    double ty = y * inv_z; ty = fmin(fmax(ty, -lim), lim); ty *= z;
    const double xx = cov3[i * 6 + 0], xy = cov3[i * 6 + 1], xz = cov3[i * 6 + 2];
    const double yy = cov3[i * 6 + 3], yz = cov3[i * 6 + 4], zz = cov3[i * 6 + 5];
    const double J00 = fx * inv_z, J02 = -fx * tx * inv_z * inv_z;
    const double J11 = fy * inv_z, J12 = -fy * ty * inv_z * inv_z;
    // M = J * S (rows 0 and 1); cov2 = M * J^T
    const double M00 = J00 * xx + J02 * xz;
    const double M01 = J00 * xy + J02 * yz;
    const double M02 = J00 * xz + J02 * zz;
    const double M10 = J11 * xy + J12 * xz;
    const double M11 = J11 * yy + J12 * yz;
    const double M12 = J11 * yz + J12 * zz;
    const double a = M00 * J00 + M02 * J02 + 0.3;
    const double b = M01 * J11 + M02 * J12;  // cov2[0,1]
    const double c = M11 * J11 + M12 * J12 + 0.3;
    const double det = a * c - b * b;
    const double inv_det = 1.0 / det;
    const double mid = 0.5 * (a + c);
    const double lam1 = mid + sqrt(fmax(0.1, mid * mid - det));
    const bool valid = (z > 0.2) && (det > 0.0);
    radii_out[i] = valid ? (float)ceil(3.0 * sqrt(lam1)) : 0.0f;

    const float op = opac[i];
    // Conservative cull radius^2: outside it, alpha < ALPHA_MIN * e^-0.05 guaranteed
    // (uses d^T Sigma^-1 d >= d^2 / lam1, lam1 >= lambda_max).
    float rc2 = -1.0f;
    if (valid) {
        const double L = log(255.0 * (double)op);
        if (L > 0.0) rc2 = (float)(2.0 * (L + 0.05) * lam1 * 1.0001);
    }
    const int r = ranks[i];
    soa[r]          = (float)px;
    soa[r + NG]     = (float)py;
    soa[r + 2 * NG] = rc2;
    soa[r + 3 * NG] = (float)(c * inv_det);   // conA
    soa[r + 4 * NG] = (float)(-b * inv_det);  // conB
    soa[r + 5 * NG] = (float)(a * inv_det);   // conC
    soa[r + 6 * NG] = op;
    soa[r + 7 * NG] = colors[i * 3 + 0];
    soa[r + 8 * NG] = colors[i * 3 + 1];
    soa[r + 9 * NG] = colors[i * 3 + 2];
}

// ---------------------------------------------------------------------------
// One 8x8 pixel tile per 64-thread block (one wave). Per 64-gaussian chunk:
// each lane tests one gaussian's cull circle vs the tile rect, ballot, then
// all lanes composite the hits in ascending (z-sorted) order.
__global__ void __launch_bounds__(64) render_kernel(const float* __restrict__ soa,
                                                    const float* __restrict__ bg,
                                                    float* __restrict__ out) {
    const int lane = threadIdx.x;
    const int tile_x = (blockIdx.x & 15) * 8;
    const int tile_y = (blockIdx.x >> 4) * 8;
    const float pxf = (float)(tile_x + (lane & 7));
    const float pyf = (float)(tile_y + (lane >> 3));
    const float tx0 = (float)tile_x, tx1 = (float)(tile_x + 7);
    const float ty0 = (float)tile_y, ty1 = (float)(tile_y + 7);

    const float* __restrict__ spx  = soa;
    const float* __restrict__ spy  = soa + NG;
    const float* __restrict__ src2 = soa + 2 * NG;
    const float* __restrict__ sA   = soa + 3 * NG;
    const float* __restrict__ sB   = soa + 4 * NG;
    const float* __restrict__ sC   = soa + 5 * NG;
    const float* __restrict__ sop  = soa + 6 * NG;
    const float* __restrict__ scr  = soa + 7 * NG;
    const float* __restrict__ scg  = soa + 8 * NG;
    const float* __restrict__ scb  = soa + 9 * NG;

    float T = 1.0f, accr = 0.0f, accg = 0.0f, accb = 0.0f;

    for (int base = 0; base < NG; base += 64) {
        // whole wave saturated -> stop (error <= 1e-4 per channel; bg term exact since bg=0)
        if (__ballot(T >= 1e-4f) == 0ull) break;
        const int g0 = base + lane;
        const float gpx = spx[g0], gpy = spy[g0], grc2 = src2[g0];
        const float ddx = fmaxf(fmaxf(tx0 - gpx, gpx - tx1), 0.0f);
        const float ddy = fmaxf(fmaxf(ty0 - gpy, gpy - ty1), 0.0f);
        unsigned long long m = __ballot(ddx * ddx + ddy * ddy <= grc2);
        while (m) {
            const int g = base + __builtin_ctzll(m);
            m &= (m - 1);
            const float A = sA[g], B = sB[g], C = sC[g];
            const float cx = spx[g], cy = spy[g], op = sop[g];
            const float dx = cx - pxf, dy = cy - pyf;
            const float power = -0.5f * (A * dx * dx + C * dy * dy) - B * dx * dy;
            const float alpha = fminf(0.99f, op * __expf(power));
            if (!(power > 0.0f) && alpha >= ALPHA_MIN) {
                const float w = alpha * T;
                accr += w * scr[g];
                accg += w * scg[g];
                accb += w * scb[g];
                T *= (1.0f - alpha);
            }
        }
    }

    const int pix = (tile_y + (lane >> 3)) * IMG_W + tile_x + (lane & 7);
    out[pix]             = accr + T * bg[0];
    out[pix + NPIX]      = accg + T * bg[1];
    out[pix + 2 * NPIX]  = accb + T * bg[2];
}

// ---------------------------------------------------------------------------
extern "C" void kernel_launch(void* const* d_in, const int* in_sizes, int n_in,
                              void* d_out, int out_size, void* d_ws, size_t ws_size,
                              hipStream_t stream) {
    const float* means  = (const float*)d_in[0];  // (N,3)
    const float* colors = (const float*)d_in[1];  // (N,3)
    const float* opac   = (const float*)d_in[2];  // (N,1)
    const float* cov3   = (const float*)d_in[3];  // (N,6)
    const float* bg     = (const float*)d_in[4];  // (3,)
    float* out = (float*)d_out;                   // img (3*128*128) then radii (2048) as float

    int* ranks = (int*)d_ws;
    float* soa = (float*)((char*)d_ws + NG * sizeof(int));

    hipMemsetAsync(ranks, 0, NG * sizeof(int), stream);
    rank_kernel<<<64, 256, 0, stream>>>(means, ranks);
    prep_kernel<<<NG / 256, 256, 0, stream>>>(means, colors, opac, cov3, ranks,
                                              out + 3 * NPIX, soa);
    render_kernel<<<256, 64, 0, stream>>>(soa, bg, out);
}

// Round 2
// 83.294 us; speedup vs baseline: 1.4387x; 1.4387x over previous
//
#include <hip/hip_runtime.h>
#include <math.h>

#define NG 2048
#define IMG_W 128
#define IMG_H 128
#define NPIX (IMG_W * IMG_H)
#define ALPHA_MIN (1.0f / 255.0f)
#define NSEG 4
#define SEG (NG / NSEG)  // 512 gaussians per z-segment

// ws layout:
//   [0, 64K)       : int ranks8[8][2048] partial stable-rank counts
//   [64K, 160K)    : float aos[2048][12] z-sorted params:
//                    px, py, rc2, A, B, C, op, cr, cg, cb, pad, pad

// ---------------------------------------------------------------------------
// Partial stable ranks (z ascending, ties by index -> matches stable argsort).
// Block (bi,bk) counts, for each i in chunk bi, how many j in chunk bk sort
// before i. No atomics: each of the 8 partial arrays is written exactly once.
__global__ void __launch_bounds__(256) rank_kernel(const float* __restrict__ means,
                                                   int* __restrict__ ranks8) {
    __shared__ float zs[256];
    const int t  = threadIdx.x;
    const int bi = blockIdx.x & 7;   // i-chunk
    const int bk = blockIdx.x >> 3;  // j-chunk
    const int j0 = bk * 256;
    zs[t] = means[(j0 + t) * 3 + 2];
    const int i = bi * 256 + t;
    const float zi = means[i * 3 + 2];
    __syncthreads();
    int cnt = 0;
#pragma unroll 8
    for (int j = 0; j < 256; ++j) {
        const float zj = zs[j];
        cnt += (zj < zi || (zj == zi && (j0 + j) < i)) ? 1 : 0;
    }
    ranks8[bk * NG + i] = cnt;
}

// ---------------------------------------------------------------------------
// Per-gaussian projection/conic (double precision keeps ceil() boundaries
// exact vs the fp32/np reference); scatter into z-sorted AoS.
__global__ void __launch_bounds__(256) prep_kernel(const float* __restrict__ means,
                                                   const float* __restrict__ colors,
                                                   const float* __restrict__ opac,
                                                   const float* __restrict__ cov3,
                                                   const int* __restrict__ ranks8,
                                                   float* __restrict__ radii_out,
                                                   float* __restrict__ aos) {
    const int i = blockIdx.x * 256 + threadIdx.x;
    if (i >= NG) return;
    const double x = means[i * 3 + 0];
    const double y = means[i * 3 + 1];
    const double z = means[i * 3 + 2];
    const double inv_z = 1.0 / z;
    const double fx = 128.0, fy = 128.0, lim = 0.65;  // W/(2*tanfov), 1.3*tanfov
    const double px = fx * x * inv_z + 64.0;
    const double py = fy * y * inv_z + 64.0;
    double tx = x * inv_z; tx = fmin(fmax(tx, -lim), lim); tx *= z;
    double ty = y * inv_z; ty = fmin(fmax(ty, -lim), lim); ty *= z;
    const double xx = cov3[i * 6 + 0], xy = cov3[i * 6 + 1], xz = cov3[i * 6 + 2];
    const double yy = cov3[i * 6 + 3], yz = cov3[i * 6 + 4], zz = cov3[i * 6 + 5];
    const double J00 = fx * inv_z, J02 = -fx * tx * inv_z * inv_z;
    const double J11 = fy * inv_z, J12 = -fy * ty * inv_z * inv_z;
    const double M00 = J00 * xx + J02 * xz;
    const double M01 = J00 * xy + J02 * yz;
    const double M02 = J00 * xz + J02 * zz;
    const double M10 = J11 * xy + J12 * xz;
    const double M11 = J11 * yy + J12 * yz;
    const double M12 = J11 * yz + J12 * zz;
    const double a = M00 * J00 + M02 * J02 + 0.3;
    const double b = M01 * J11 + M02 * J12;  // cov2[0,1]
    const double c = M11 * J11 + M12 * J12 + 0.3;
    const double det = a * c - b * b;
    const double inv_det = 1.0 / det;
    const double mid = 0.5 * (a + c);
    const double lam1 = mid + sqrt(fmax(0.1, mid * mid - det));
    const bool valid = (z > 0.2) && (det > 0.0);
    radii_out[i] = valid ? (float)ceil(3.0 * sqrt(lam1)) : 0.0f;

    const float op = opac[i];
    // Conservative cull radius^2: outside it alpha < ALPHA_MIN * e^-0.05
    // guaranteed (d^T Sigma^-1 d >= d^2 / lam1, lam1 >= lambda_max).
    float rc2 = -1.0f;
    if (valid) {
        const double L = log(255.0 * (double)op);
        if (L > 0.0) rc2 = (float)(2.0 * (L + 0.05) * lam1 * 1.0001);
    }
    int r = 0;
#pragma unroll
    for (int k = 0; k < 8; ++k) r += ranks8[k * NG + i];

    float4* dst = (float4*)(aos + r * 12);
    dst[0] = make_float4((float)px, (float)py, rc2, (float)(c * inv_det));
    dst[1] = make_float4((float)(-b * inv_det), (float)(a * inv_det), op,
                         colors[i * 3 + 0]);
    dst[2] = make_float4(colors[i * 3 + 1], colors[i * 3 + 2], 0.0f, 0.0f);
}

// ---------------------------------------------------------------------------
// 256 blocks x 256 threads. Block = one 8x8 pixel tile; each of its 4 waves
// composites a disjoint z-segment of 512 gaussians, then LDS merge:
//   img = sum_s (prod_{s'<s} T_s') * acc_s ,  T = prod_s T_s  (exact).
// Inner loop: per-lane AoS float4 loads (pipelined), ballot over the tile
// cull test, then v_readlane broadcasts -> zero memory ops per hit.
__global__ void __launch_bounds__(256) render_kernel(const float* __restrict__ aos,
                                                     const float* __restrict__ bg,
                                                     float* __restrict__ out) {
    const int lane = threadIdx.x & 63;
    const int wave = threadIdx.x >> 6;
    const int tile_x = (blockIdx.x & 15) * 8;
    const int tile_y = (blockIdx.x >> 4) * 8;
    const float pxf = (float)(tile_x + (lane & 7));
    const float pyf = (float)(tile_y + (lane >> 3));
    const float tx0 = (float)tile_x, tx1 = (float)(tile_x + 7);
    const float ty0 = (float)tile_y, ty1 = (float)(tile_y + 7);

    const float4* __restrict__ av = (const float4*)aos;

    float T = 1.0f, accr = 0.0f, accg = 0.0f, accb = 0.0f;

    int g = wave * SEG + lane;
    float4 a0 = av[g * 3 + 0];
    float4 a1 = av[g * 3 + 1];
    float4 a2 = av[g * 3 + 2];

#define RL(x) __int_as_float(__builtin_amdgcn_readlane(__float_as_int(x), j))
    for (int c = 0; c < SEG / 64; ++c) {
        float4 b0, b1, b2;
        if (c + 1 < SEG / 64) {           // prefetch next chunk
            const int gn = (g + 64) * 3;
            b0 = av[gn + 0]; b1 = av[gn + 1]; b2 = av[gn + 2];
        }
        // tile-rect vs cull-circle test for this lane's gaussian
        const float ddx = fmaxf(fmaxf(tx0 - a0.x, a0.x - tx1), 0.0f);
        const float ddy = fmaxf(fmaxf(ty0 - a0.y, a0.y - ty1), 0.0f);
        unsigned long long m = __ballot(ddx * ddx + ddy * ddy <= a0.z);
        while (m) {
            const int j = __builtin_ctzll(m);
            m &= (m - 1);
            const float cx = RL(a0.x), cy = RL(a0.y);
            const float A = RL(a0.w), B = RL(a1.x), C = RL(a1.y);
            const float op = RL(a1.z);
            const float cr = RL(a1.w), cg = RL(a2.x), cb = RL(a2.y);
            const float dx = cx - pxf, dy = cy - pyf;
            const float power = -0.5f * (A * dx * dx + C * dy * dy) - B * dx * dy;
            const float alpha = fminf(0.99f, op * __expf(power));
            const bool keep = (power <= 0.0f) & (alpha >= ALPHA_MIN);
            const float ae = keep ? alpha : 0.0f;
            const float w = ae * T;
            accr = fmaf(w, cr, accr);
            accg = fmaf(w, cg, accg);
            accb = fmaf(w, cb, accb);
            T *= (1.0f - ae);
        }
        // whole-wave saturated -> done (residual contribution < 1e-4)
        if (__ballot(T >= 1e-4f) == 0ull) break;
        a0 = b0; a1 = b1; a2 = b2; g += 64;
    }
#undef RL

    // merge the 4 z-segments, front to back
    __shared__ float part[NSEG][4][64];
    part[wave][0][lane] = accr;
    part[wave][1][lane] = accg;
    part[wave][2][lane] = accb;
    part[wave][3][lane] = T;
    __syncthreads();
    if (wave == 0) {
        float R = part[0][0][lane], G = part[0][1][lane], Bc = part[0][2][lane];
        float Tt = part[0][3][lane];
#pragma unroll
        for (int s = 1; s < NSEG; ++s) {
            R  = fmaf(Tt, part[s][0][lane], R);
            G  = fmaf(Tt, part[s][1][lane], G);
            Bc = fmaf(Tt, part[s][2][lane], Bc);
            Tt *= part[s][3][lane];
        }
        const int pix = (tile_y + (lane >> 3)) * IMG_W + tile_x + (lane & 7);
        out[pix]            = fmaf(Tt, bg[0], R);
        out[pix + NPIX]     = fmaf(Tt, bg[1], G);
        out[pix + 2 * NPIX] = fmaf(Tt, bg[2], Bc);
    }
}

// ---------------------------------------------------------------------------
extern "C" void kernel_launch(void* const* d_in, const int* in_sizes, int n_in,
                              void* d_out, int out_size, void* d_ws, size_t ws_size,
                              hipStream_t stream) {
    const float* means  = (const float*)d_in[0];  // (N,3)
    const float* colors = (const float*)d_in[1];  // (N,3)
    const float* opac   = (const float*)d_in[2];  // (N,1)
    const float* cov3   = (const float*)d_in[3];  // (N,6)
    const float* bg     = (const float*)d_in[4];  // (3,)
    float* out = (float*)d_out;  // img (3*128*128) then radii (2048) as float

    int*   ranks8 = (int*)d_ws;
    float* aos    = (float*)((char*)d_ws + 8 * NG * sizeof(int));

    rank_kernel<<<64, 256, 0, stream>>>(means, ranks8);
    prep_kernel<<<NG / 256, 256, 0, stream>>>(means, colors, opac, cov3, ranks8,
                                              out + 3 * NPIX, aos);
    render_kernel<<<256, 256, 0, stream>>>(aos, bg, out);
}